// Round 12
// baseline (1284.689 us; speedup 1.0000x reference)
//
#include <hip/hip_runtime.h>
#include <math.h>

#define NEG_SLOPE 0.2f

typedef __bf16 bf16x8 __attribute__((ext_vector_type(8)));
typedef float f32x4 __attribute__((ext_vector_type(4)));

// f32 -> bf16 bits, round-to-nearest-even
__device__ __forceinline__ ushort f2bf(float x) {
  union { float f; unsigned u; } v; v.f = x;
  unsigned r = v.u + 0x7fffu + ((v.u >> 16) & 1u);
  return (ushort)(r >> 16);
}
__device__ __forceinline__ float bf2f(ushort b) {
  union { unsigned u; float f; } v; v.u = (unsigned)b << 16;
  return v.f;
}

// LDS swizzle for [.][512B] rows (f-tile); period-32 in rows (row&7, (row>>3)&3)
__device__ __forceinline__ int swz(int m) {
  return ((m & 7) << 4) | (((m >> 3) & 3) << 7);
}

// atomic float max via int/uint trick (works for mixed signs, init -inf)
__device__ __forceinline__ void atomicMaxF32(float* addr, float val) {
  if (val >= 0.f) {
    atomicMax((int*)addr, __float_as_int(val));
  } else {
    atomicMin((unsigned int*)addr, __float_as_uint(val));
  }
}

// ---------------- K0: init emax=-inf, asum=0, agg=0 ----------------
__global__ void k_init(float* __restrict__ emax, float* __restrict__ asum,
                       float* __restrict__ agg, int n) {
  int i = blockIdx.x * 256 + threadIdx.x;
  if (i < n * 4) { emax[i] = -INFINITY; asum[i] = 0.f; }
  if (i < n * 64) agg[i] = 0.f;
}

// ---------------- K prep: build concatenated bf16 weights ----------------
// WcatT[c][k], c<256, k<192, k-order [Wfij(0..63) | Wni(64..127) | Wnj(128..191)]
// WpeT[n][k] = Wpe[k][n]  (k<256, n<64)
__global__ void k_prep(const float* __restrict__ Wfij,
                       const float* __restrict__ Wni,
                       const float* __restrict__ Wnj,
                       const float* __restrict__ Wpe,
                       ushort* __restrict__ WcatT, ushort* __restrict__ WpeT) {
  int i = blockIdx.x * 256 + threadIdx.x;
  if (i < 49152) {
    int c = i / 192, k = i % 192;
    float v = (k < 64) ? Wfij[k * 256 + c]
            : (k < 128) ? Wni[(k - 64) * 256 + c]
                        : Wnj[(k - 128) * 256 + c];
    WcatT[c * 192 + k] = f2bf(v);
  }
  if (i < 16384) {
    int k2 = i >> 6, n2 = i & 63;  // Wpe[k2][n2]
    WpeT[n2 * 256 + k2] = f2bf(Wpe[i]);
  }
}

// ---------------- K1: node transforms: hE_bf(bf16), hq(bf16) ----------------
__global__ __launch_bounds__(256) void k_node(
    const float* __restrict__ hE,
    const float* __restrict__ Wnode, const float* __restrict__ bnode,
    const float* __restrict__ Wpn,
    ushort* __restrict__ hE_bf, ushort* __restrict__ hq, int n) {
  __shared__ float hEt[64 * 36];    // transposed [k][m], stride 36 (pad)
  __shared__ float hpl[32 * 260];   // hp tile [m][c], stride 260 (pad)
  const int tid = threadIdx.x;
  const int n0 = blockIdx.x * 32;

#pragma unroll
  for (int i = 0; i < 8; ++i) {
    int flat = tid + i * 256;
    int m = flat >> 6, k = flat & 63;
    float v = (n0 + m < n) ? hE[(size_t)(n0 + m) * 64 + k] : 0.f;
    hEt[k * 36 + m] = v;
    if (n0 + m < n) hE_bf[(size_t)(n0 + m) * 64 + k] = f2bf(v);
  }
  __syncthreads();

  const int tm = tid >> 5, tc = tid & 31, c0 = tc * 8;

  // hp pass
  {
    float acc[4][8];
#pragma unroll
    for (int mm = 0; mm < 4; ++mm)
#pragma unroll
      for (int j = 0; j < 8; ++j) acc[mm][j] = 0.f;

    for (int k = 0; k < 64; ++k) {
      float4 h4 = *(const float4*)&hEt[k * 36 + tm * 4];
      float4 w0 = *(const float4*)&Wnode[k * 256 + c0];
      float4 w1 = *(const float4*)&Wnode[k * 256 + c0 + 4];
      float hv[4] = {h4.x, h4.y, h4.z, h4.w};
      float wv[8] = {w0.x, w0.y, w0.z, w0.w, w1.x, w1.y, w1.z, w1.w};
#pragma unroll
      for (int mm = 0; mm < 4; ++mm)
#pragma unroll
        for (int j = 0; j < 8; ++j) acc[mm][j] += hv[mm] * wv[j];
    }
#pragma unroll
    for (int mm = 0; mm < 4; ++mm) {
      int m = tm * 4 + mm;
#pragma unroll
      for (int j = 0; j < 8; ++j)
        hpl[m * 260 + c0 + j] = acc[mm][j] + bnode[c0 + j];
    }
  }
  __syncthreads();

  // hq pass: per-head 64x64 projection. col c0+j lives in head hh.
  const int hh = tc >> 3, dc0 = (tc & 7) * 8;
  float acc[4][8];
#pragma unroll
  for (int mm = 0; mm < 4; ++mm)
#pragma unroll
    for (int j = 0; j < 8; ++j) acc[mm][j] = 0.f;

  for (int k = 0; k < 64; ++k) {
    float4 w0 = *(const float4*)&Wpn[(size_t)(hh * 64 + k) * 64 + dc0];
    float4 w1 = *(const float4*)&Wpn[(size_t)(hh * 64 + k) * 64 + dc0 + 4];
    float wv[8] = {w0.x, w0.y, w0.z, w0.w, w1.x, w1.y, w1.z, w1.w};
#pragma unroll
    for (int mm = 0; mm < 4; ++mm) {
      float hv = hpl[(tm * 4 + mm) * 260 + hh * 64 + k];
#pragma unroll
      for (int j = 0; j < 8; ++j) acc[mm][j] += hv * wv[j];
    }
  }
#pragma unroll
  for (int mm = 0; mm < 4; ++mm) {
    int m = tm * 4 + mm;
    if (n0 + m < n) {
      ushort u[8];
#pragma unroll
      for (int j = 0; j < 8; ++j) u[j] = f2bf(acc[mm][j]);
      *(uint4*)&hq[(size_t)(n0 + m) * 256 + c0] = *(const uint4*)u;
    }
  }
}

// ---------------- K2: edge kernel (r8 structure, M=64 tiles) ----------------
// REVERT of the r10/r11 pipeline (both slower + over-fetching). r8's plain
// 3-barrier persistent loop, with the tile doubled to 64 edges: halves the
// number of serial per-tile chain traversals (12500 vs 25000) at constant
// occupancy (2 blocks/CU), constant traffic, constant weight registers.
__global__ __launch_bounds__(256, 2) void k_edge(
    const float* __restrict__ hH,
    const int* __restrict__ src, const int* __restrict__ dst,
    const ushort* __restrict__ WcatT,  // [256][192] bf16
    const float* __restrict__ attn,
    const ushort* __restrict__ WpeT,   // [64][256] bf16
    const float* __restrict__ bpe,
    const ushort* __restrict__ hE_bf,  // [n][64] bf16
    float* __restrict__ e_ws, float* __restrict__ emax,
    float* __restrict__ out1, int ntiles) {
  // A-tile [64][384B] = 24576, F-tile [64][512B] = 32768 -> 57344B
  __shared__ __align__(16) char smem[57344];
  char* ab = smem;
  char* fb = smem + 24576;

  const int tid = threadIdx.x;
  const int w = tid >> 6, l = tid & 63;
  const int lr = l & 15, lk = l >> 4;
  const int swa = (lr & 7) << 4;
  const int stm = tid >> 3, sts = tid & 7;  // staging: 8 thr/row, 2 rows/thr

  // ---- one-time: hoist all weights for this wave into registers
  bf16x8 bw1[6][4];
#pragma unroll
  for (int ks = 0; ks < 6; ++ks)
#pragma unroll
    for (int nt = 0; nt < 4; ++nt)
      bw1[ks][nt] = *(const bf16x8*)(WcatT +
          (size_t)(w * 64 + nt * 16 + lr) * 192 + ks * 32 + lk * 8);
  bf16x8 bw2[8];
#pragma unroll
  for (int ks = 0; ks < 8; ++ks)
    bw2[ks] = *(const bf16x8*)(WpeT +
        (size_t)(w * 16 + lr) * 256 + ks * 32 + lk * 8);
  float av[4];
#pragma unroll
  for (int nt = 0; nt < 4; ++nt) av[nt] = attn[w * 64 + nt * 16 + lr];
  const float bpv = bpe[w * 16 + lr];
  const int sw0 = swz(lr), sw1 = swz(16 + lr);
  const int sw2 = swz(32 + lr), sw3 = swz(48 + lr);

  for (int tile = blockIdx.x; tile < ntiles; tile += gridDim.x) {
    const int e0 = tile * 64;

    // ---- Phase 0: stage A-tile = [hH | hE_src | hE_dst] bf16, 64 rows
#pragma unroll
    for (int mi = 0; mi < 2; ++mi) {
      int row = stm + mi * 32;
      int ei = e0 + row;
      int sn = src[ei], dn = dst[ei];
      char* arow = ab + row * 384;
      int swm = (row & 7) << 4;
      const float* p = hH + (size_t)ei * 64 + sts * 8;
      float4 x = *(const float4*)p;
      float4 y = *(const float4*)(p + 4);
      ushort u[8] = {f2bf(x.x), f2bf(x.y), f2bf(x.z), f2bf(x.w),
                     f2bf(y.x), f2bf(y.y), f2bf(y.z), f2bf(y.w)};
      *(uint4*)(arow + ((sts * 16) ^ swm)) = *(const uint4*)u;
      *(uint4*)(arow + (128 + ((sts * 16) ^ swm))) =
          *(const uint4*)(hE_bf + (size_t)sn * 64 + sts * 8);
      *(uint4*)(arow + (256 + ((sts * 16) ^ swm))) =
          *(const uint4*)(hE_bf + (size_t)dn * 64 + sts * 8);
    }
    __syncthreads();

    // ---- GEMM1: f_pre = A(64x192) @ Wcat(192x256), wave slab [w*64,(w+1)*64)
    f32x4 acc[4][4];
#pragma unroll
    for (int mt = 0; mt < 4; ++mt)
#pragma unroll
      for (int nt = 0; nt < 4; ++nt) acc[mt][nt] = (f32x4){0.f, 0.f, 0.f, 0.f};

#pragma unroll
    for (int ks = 0; ks < 6; ++ks) {
      int sec = (ks >> 1) << 7;               // 128B section base
      int off = ((ks & 1) << 6) | (lk << 4);  // 0..127 within section
      bf16x8 a[4];
#pragma unroll
      for (int mt = 0; mt < 4; ++mt)
        a[mt] = *(const bf16x8*)(ab + (mt * 16 + lr) * 384 + sec + (off ^ swa));
#pragma unroll
      for (int nt = 0; nt < 4; ++nt) {
#pragma unroll
        for (int mt = 0; mt < 4; ++mt)
          acc[mt][nt] = __builtin_amdgcn_mfma_f32_16x16x32_bf16(
              a[mt], bw1[ks][nt], acc[mt][nt], 0, 0, 0);
      }
    }

    // ---- leaky, logits, f -> bf16 f-tile, e_ws + atomicMax
#pragma unroll
    for (int mt = 0; mt < 4; ++mt) {
#pragma unroll
      for (int r = 0; r < 4; ++r) {
        int m = mt * 16 + lk * 4 + r;
        char* rowp = fb + m * 512;
        int sw = swz(m);
        float p = 0.f;
#pragma unroll
        for (int nt = 0; nt < 4; ++nt) {
          int c = w * 64 + nt * 16 + lr;
          float v = acc[mt][nt][r];
          v = (v >= 0.f) ? v : NEG_SLOPE * v;
          p += v * av[nt];
          *(ushort*)(rowp + ((c * 2) ^ sw)) = f2bf(v);
        }
        p += __shfl_xor(p, 1);
        p += __shfl_xor(p, 2);
        p += __shfl_xor(p, 4);
        p += __shfl_xor(p, 8);
        if (lr == 0) {
          e_ws[(size_t)(e0 + m) * 4 + w] = p;
          atomicMaxF32(&emax[(size_t)dst[e0 + m] * 4 + w], p);
        }
      }
    }
    __syncthreads();

    // ---- GEMM2: out1 = f @ Wpe; wave w owns cols [w*16,(w+1)*16)
    f32x4 acc2[4];
#pragma unroll
    for (int mt = 0; mt < 4; ++mt) acc2[mt] = (f32x4){0.f, 0.f, 0.f, 0.f};
#pragma unroll
    for (int ks = 0; ks < 8; ++ks) {
      int ko = (ks * 32 + lk * 8) * 2;
      bf16x8 a0 = *(const bf16x8*)(fb + lr * 512 + (ko ^ sw0));
      bf16x8 a1 = *(const bf16x8*)(fb + (16 + lr) * 512 + (ko ^ sw1));
      bf16x8 a2 = *(const bf16x8*)(fb + (32 + lr) * 512 + (ko ^ sw2));
      bf16x8 a3 = *(const bf16x8*)(fb + (48 + lr) * 512 + (ko ^ sw3));
      acc2[0] =
          __builtin_amdgcn_mfma_f32_16x16x32_bf16(a0, bw2[ks], acc2[0], 0, 0, 0);
      acc2[1] =
          __builtin_amdgcn_mfma_f32_16x16x32_bf16(a1, bw2[ks], acc2[1], 0, 0, 0);
      acc2[2] =
          __builtin_amdgcn_mfma_f32_16x16x32_bf16(a2, bw2[ks], acc2[2], 0, 0, 0);
      acc2[3] =
          __builtin_amdgcn_mfma_f32_16x16x32_bf16(a3, bw2[ks], acc2[3], 0, 0, 0);
    }

    // epilogue: + hH (bf16, from A-tile) + bpe
#pragma unroll
    for (int mt = 0; mt < 4; ++mt)
#pragma unroll
      for (int r = 0; r < 4; ++r) {
        int m = mt * 16 + lk * 4 + r;
        int swm = (m & 7) << 4;
        ushort h =
            *(const ushort*)(ab + m * 384 + ((((w * 16 + lr) * 2)) ^ swm));
        size_t idx = (size_t)(e0 + m) * 64 + w * 16 + lr;
        out1[idx] = acc2[mt][r] + bf2f(h) + bpv;
      }
    __syncthreads();  // protect LDS before next tile's staging
  }
}

// ---------------- K3a: a = exp(e - emax[dst]); asum += a ----------------
__global__ void k3a(const float* __restrict__ e_ws, const int* __restrict__ dst,
                    const float* __restrict__ emax, float* __restrict__ a_ws,
                    float* __restrict__ asum, int E4) {
  int gid = blockIdx.x * 256 + threadIdx.x;
  if (gid >= E4) return;
  int e = gid >> 2, h = gid & 3;
  int dn = dst[e];
  float av = expf(e_ws[gid] - emax[dn * 4 + h]);
  a_ws[gid] = av;
  atomicAdd(&asum[dn * 4 + h], av);
}

// ---------------- K3b: agg[dst] += sum_h (a/asum) * hq[src,h,:] ----------------
__global__ __launch_bounds__(256) void k3b(
    const float* __restrict__ a_ws, const float* __restrict__ asum,
    const int* __restrict__ src, const int* __restrict__ dst,
    const ushort* __restrict__ hq, float* __restrict__ agg, int E) {
  int e = blockIdx.x * 4 + (threadIdx.x >> 6);
  if (e >= E) return;
  int d = threadIdx.x & 63;
  int sn = src[e], dn = dst[e];
  float w0 = a_ws[e * 4 + 0] / asum[dn * 4 + 0];
  float w1 = a_ws[e * 4 + 1] / asum[dn * 4 + 1];
  float w2 = a_ws[e * 4 + 2] / asum[dn * 4 + 2];
  float w3 = a_ws[e * 4 + 3] / asum[dn * 4 + 3];
  const ushort* hqp = hq + (size_t)sn * 256;
  float y = w0 * bf2f(hqp[d]) + w1 * bf2f(hqp[64 + d]) +
            w2 * bf2f(hqp[128 + d]) + w3 * bf2f(hqp[192 + d]);
  atomicAdd(&agg[(size_t)dn * 64 + d], y);
}

// ---------------- K4: out0 = hE + agg + bp_node ----------------
__global__ void k4(const float* __restrict__ hE, const float* __restrict__ agg,
                   const float* __restrict__ bpn, float* __restrict__ out0,
                   int ND) {
  int i = blockIdx.x * 256 + threadIdx.x;
  if (i < ND) out0[i] = hE[i] + agg[i] + bpn[i & 63];
}

extern "C" void kernel_launch(void* const* d_in, const int* in_sizes, int n_in,
                              void* d_out, int out_size, void* d_ws, size_t ws_size,
                              hipStream_t stream) {
  const float* h_E    = (const float*)d_in[0];
  const float* h_H    = (const float*)d_in[1];
  const int*   src    = (const int*)d_in[2];
  const int*   dst    = (const int*)d_in[3];
  const float* W_node = (const float*)d_in[4];
  const float* b_node = (const float*)d_in[5];
  const float* W_ni   = (const float*)d_in[6];
  const float* W_nj   = (const float*)d_in[7];
  const float* W_fij  = (const float*)d_in[8];
  const float* attn   = (const float*)d_in[9];
  const float* Wp_node= (const float*)d_in[10];
  const float* bp_node= (const float*)d_in[11];
  const float* Wp_edge= (const float*)d_in[12];
  const float* bp_edge= (const float*)d_in[13];

  const int n = in_sizes[0] / 64;   // 50000 nodes
  const int e = in_sizes[1] / 64;   // 800000 edges

  // workspace layout
  ushort* ws_hEbf = (ushort*)d_ws;                      // n*64 bf16
  ushort* ws_hq   = ws_hEbf + (size_t)n * 64;           // n*256 bf16
  float*  ws_e    = (float*)(ws_hq + (size_t)n * 256);  // e*4
  float*  ws_a    = ws_e + (size_t)e * 4;               // e*4
  float*  ws_emax = ws_a + (size_t)e * 4;               // n*4
  float*  ws_asum = ws_emax + (size_t)n * 4;            // n*4
  float*  ws_agg  = ws_asum + (size_t)n * 4;            // n*64
  ushort* ws_Wcat = (ushort*)(ws_agg + (size_t)n * 64); // 256*192 bf16
  ushort* ws_WpeT = ws_Wcat + 49152;                    // 64*256 bf16

  float* out0 = (float*)d_out;               // (n,64)
  float* out1 = out0 + (size_t)n * 64;       // (e,64)

  {
    int total = n * 64;
    k_init<<<(total + 255) / 256, 256, 0, stream>>>(ws_emax, ws_asum, ws_agg, n);
  }
  k_prep<<<192, 256, 0, stream>>>(W_fij, W_ni, W_nj, Wp_edge, ws_Wcat, ws_WpeT);
  {
    int blocks = (n + 31) / 32;
    k_node<<<blocks, 256, 0, stream>>>(h_E, W_node, b_node, Wp_node,
                                       ws_hEbf, ws_hq, n);
  }
  {
    int ntiles = e / 64;  // E=800000 divisible by 64
    k_edge<<<1024, 256, 0, stream>>>(h_H, src, dst, ws_Wcat, attn, ws_WpeT,
                                     bp_edge, ws_hEbf, ws_e, ws_emax, out1,
                                     ntiles);
  }
  {
    int total = e * 4;
    k3a<<<(total + 255) / 256, 256, 0, stream>>>(ws_e, dst, ws_emax, ws_a,
                                                 ws_asum, total);
  }
  {
    int blocks = (e + 3) / 4;
    k3b<<<blocks, 256, 0, stream>>>(ws_a, ws_asum, src, dst, ws_hq, ws_agg, e);
  }
  {
    int total = n * 64;
    k4<<<(total + 255) / 256, 256, 0, stream>>>(h_E, ws_agg, bp_node, out0,
                                                total);
  }
}

// Round 14
// 680.091 us; speedup vs baseline: 1.8890x; 1.8890x over previous
//
#include <hip/hip_runtime.h>
#include <math.h>

#define NEG_SLOPE 0.2f

typedef __bf16 bf16x8 __attribute__((ext_vector_type(8)));
typedef float f32x4 __attribute__((ext_vector_type(4)));
typedef float f32x4v __attribute__((ext_vector_type(4)));  // for nt-load

// f32 -> bf16 bits, round-to-nearest-even
__device__ __forceinline__ ushort f2bf(float x) {
  union { float f; unsigned u; } v; v.f = x;
  unsigned r = v.u + 0x7fffu + ((v.u >> 16) & 1u);
  return (ushort)(r >> 16);
}
__device__ __forceinline__ float bf2f(ushort b) {
  union { unsigned u; float f; } v; v.u = (unsigned)b << 16;
  return v.f;
}

// LDS swizzle for [32][512B] rows (f-tile)
__device__ __forceinline__ int swz(int m) {
  return ((m & 7) << 4) | (((m >> 3) & 3) << 7);
}

// atomic float max via int/uint trick (works for mixed signs, init -inf)
__device__ __forceinline__ void atomicMaxF32(float* addr, float val) {
  if (val >= 0.f) {
    atomicMax((int*)addr, __float_as_int(val));
  } else {
    atomicMin((unsigned int*)addr, __float_as_uint(val));
  }
}

// ---------------- K0: init emax=-inf, asum=0, out0 = hE + bpn ----------------
// (k4 is fused away: k3b accumulates straight into out0.)
__global__ void k_init(float* __restrict__ emax, float* __restrict__ asum,
                       const float* __restrict__ hE,
                       const float* __restrict__ bpn,
                       float* __restrict__ out0, int n) {
  int i = blockIdx.x * 256 + threadIdx.x;
  if (i < n * 4) { emax[i] = -INFINITY; asum[i] = 0.f; }
  if (i < n * 64) out0[i] = hE[i] + bpn[i & 63];
}

// ---------------- K prep: build concatenated bf16 weights ----------------
// WcatT[c][k], c<256, k<192, k-order [Wfij(0..63) | Wni(64..127) | Wnj(128..191)]
// WpeT[n][k] = Wpe[k][n]  (k<256, n<64)
__global__ void k_prep(const float* __restrict__ Wfij,
                       const float* __restrict__ Wni,
                       const float* __restrict__ Wnj,
                       const float* __restrict__ Wpe,
                       ushort* __restrict__ WcatT, ushort* __restrict__ WpeT) {
  int i = blockIdx.x * 256 + threadIdx.x;
  if (i < 49152) {
    int c = i / 192, k = i % 192;
    float v = (k < 64) ? Wfij[k * 256 + c]
            : (k < 128) ? Wni[(k - 64) * 256 + c]
                        : Wnj[(k - 128) * 256 + c];
    WcatT[c * 192 + k] = f2bf(v);
  }
  if (i < 16384) {
    int k2 = i >> 6, n2 = i & 63;  // Wpe[k2][n2]
    WpeT[n2 * 256 + k2] = f2bf(Wpe[i]);
  }
}

// ---------------- K1: node transforms: hE_bf(bf16), hq(bf16) ----------------
__global__ __launch_bounds__(256) void k_node(
    const float* __restrict__ hE,
    const float* __restrict__ Wnode, const float* __restrict__ bnode,
    const float* __restrict__ Wpn,
    ushort* __restrict__ hE_bf, ushort* __restrict__ hq, int n) {
  __shared__ float hEt[64 * 36];    // transposed [k][m], stride 36 (pad)
  __shared__ float hpl[32 * 260];   // hp tile [m][c], stride 260 (pad)
  const int tid = threadIdx.x;
  const int n0 = blockIdx.x * 32;

#pragma unroll
  for (int i = 0; i < 8; ++i) {
    int flat = tid + i * 256;
    int m = flat >> 6, k = flat & 63;
    float v = (n0 + m < n) ? hE[(size_t)(n0 + m) * 64 + k] : 0.f;
    hEt[k * 36 + m] = v;
    if (n0 + m < n) hE_bf[(size_t)(n0 + m) * 64 + k] = f2bf(v);
  }
  __syncthreads();

  const int tm = tid >> 5, tc = tid & 31, c0 = tc * 8;

  // hp pass
  {
    float acc[4][8];
#pragma unroll
    for (int mm = 0; mm < 4; ++mm)
#pragma unroll
      for (int j = 0; j < 8; ++j) acc[mm][j] = 0.f;

    for (int k = 0; k < 64; ++k) {
      float4 h4 = *(const float4*)&hEt[k * 36 + tm * 4];
      float4 w0 = *(const float4*)&Wnode[k * 256 + c0];
      float4 w1 = *(const float4*)&Wnode[k * 256 + c0 + 4];
      float hv[4] = {h4.x, h4.y, h4.z, h4.w};
      float wv[8] = {w0.x, w0.y, w0.z, w0.w, w1.x, w1.y, w1.z, w1.w};
#pragma unroll
      for (int mm = 0; mm < 4; ++mm)
#pragma unroll
        for (int j = 0; j < 8; ++j) acc[mm][j] += hv[mm] * wv[j];
    }
#pragma unroll
    for (int mm = 0; mm < 4; ++mm) {
      int m = tm * 4 + mm;
#pragma unroll
      for (int j = 0; j < 8; ++j)
        hpl[m * 260 + c0 + j] = acc[mm][j] + bnode[c0 + j];
    }
  }
  __syncthreads();

  // hq pass: per-head 64x64 projection. col c0+j lives in head hh.
  const int hh = tc >> 3, dc0 = (tc & 7) * 8;
  float acc[4][8];
#pragma unroll
  for (int mm = 0; mm < 4; ++mm)
#pragma unroll
    for (int j = 0; j < 8; ++j) acc[mm][j] = 0.f;

  for (int k = 0; k < 64; ++k) {
    float4 w0 = *(const float4*)&Wpn[(size_t)(hh * 64 + k) * 64 + dc0];
    float4 w1 = *(const float4*)&Wpn[(size_t)(hh * 64 + k) * 64 + dc0 + 4];
    float wv[8] = {w0.x, w0.y, w0.z, w0.w, w1.x, w1.y, w1.z, w1.w};
#pragma unroll
    for (int mm = 0; mm < 4; ++mm) {
      float hv = hpl[(tm * 4 + mm) * 260 + hh * 64 + k];
#pragma unroll
      for (int j = 0; j < 8; ++j) acc[mm][j] += hv * wv[j];
    }
  }
#pragma unroll
  for (int mm = 0; mm < 4; ++mm) {
    int m = tm * 4 + mm;
    if (n0 + m < n) {
      ushort u[8];
#pragma unroll
      for (int j = 0; j < 8; ++j) u[j] = f2bf(acc[mm][j]);
      *(uint4*)&hq[(size_t)(n0 + m) * 256 + c0] = *(const uint4*)u;
    }
  }
}

// ---------------- K2: edge kernel (r8 champion + non-temporal streams) ------
// EXACT r8 structure (M=32, 3 barriers, persistent grid 1024, reg weights —
// the local optimum that beat r9-r12's restructures). Only change: hH loads
// and out1 stores are NON-TEMPORAL (via ext_vector_type(4) float, which the
// builtin accepts — HIP's float4 struct does not compile). Both streams are
// touched exactly once; their 408MB combined was evicting the reused gather
// set (hE_bf 6.4MB, weights) from the L3 capacity cliff (r10/r12 lesson).
__global__ __launch_bounds__(256, 2) void k_edge(
    const float* __restrict__ hH,
    const int* __restrict__ src, const int* __restrict__ dst,
    const ushort* __restrict__ WcatT,  // [256][192] bf16
    const float* __restrict__ attn,
    const ushort* __restrict__ WpeT,   // [64][256] bf16
    const float* __restrict__ bpe,
    const ushort* __restrict__ hE_bf,  // [n][64] bf16
    float* __restrict__ e_ws, float* __restrict__ emax,
    float* __restrict__ out1, int ntiles) {
  __shared__ __align__(16) char smem[32 * 384 + 32 * 512];  // 28672B
  char* ab = smem;            // A-tile [32][384B]
  char* fb = smem + 12288;    // f-tile [32][512B]

  const int tid = threadIdx.x;
  const int w = tid >> 6, l = tid & 63;
  const int lr = l & 15, lk = l >> 4;
  const int swa = (lr & 7) << 4;
  const int stm = tid >> 3, sts = tid & 7;  // staging role: 8 thr/edge
  const int swm = (stm & 7) << 4;

  // ---- one-time: hoist all weights for this wave into registers
  bf16x8 bw1[6][4];
#pragma unroll
  for (int ks = 0; ks < 6; ++ks)
#pragma unroll
    for (int nt = 0; nt < 4; ++nt)
      bw1[ks][nt] = *(const bf16x8*)(WcatT +
          (size_t)(w * 64 + nt * 16 + lr) * 192 + ks * 32 + lk * 8);
  bf16x8 bw2[8];
#pragma unroll
  for (int ks = 0; ks < 8; ++ks)
    bw2[ks] = *(const bf16x8*)(WpeT +
        (size_t)(w * 16 + lr) * 256 + ks * 32 + lk * 8);
  float av[4];
#pragma unroll
  for (int nt = 0; nt < 4; ++nt) av[nt] = attn[w * 64 + nt * 16 + lr];
  const float bpv = bpe[w * 16 + lr];
  const int sw0 = swz(lr), sw1 = swz(16 + lr);

  for (int tile = blockIdx.x; tile < ntiles; tile += gridDim.x) {
    const int e0 = tile * 32;

    // ---- Phase 0: stage A-tile = [hH | hE_src | hE_dst] as bf16
    {
      int sn = src[e0 + stm], dn = dst[e0 + stm];
      char* arow = ab + stm * 384;
      // hH: streamed exactly once -> non-temporal (keep L3 for gathers)
      const f32x4v* p =
          (const f32x4v*)(hH + (size_t)(e0 + stm) * 64 + sts * 8);
      f32x4v x = __builtin_nontemporal_load(p);
      f32x4v y = __builtin_nontemporal_load(p + 1);
      ushort u[8] = {f2bf(x[0]), f2bf(x[1]), f2bf(x[2]), f2bf(x[3]),
                     f2bf(y[0]), f2bf(y[1]), f2bf(y[2]), f2bf(y[3])};
      *(uint4*)(arow + ((sts * 16) ^ swm)) = *(const uint4*)u;
      *(uint4*)(arow + (128 + ((sts * 16) ^ swm))) =
          *(const uint4*)(hE_bf + (size_t)sn * 64 + sts * 8);
      *(uint4*)(arow + (256 + ((sts * 16) ^ swm))) =
          *(const uint4*)(hE_bf + (size_t)dn * 64 + sts * 8);
    }
    __syncthreads();

    // ---- GEMM1: f_pre = A(32x192) @ Wcat(192x256), wave slab [w*64,(w+1)*64)
    f32x4 acc[2][4];
#pragma unroll
    for (int mt = 0; mt < 2; ++mt)
#pragma unroll
      for (int nt = 0; nt < 4; ++nt) acc[mt][nt] = (f32x4){0.f, 0.f, 0.f, 0.f};

#pragma unroll
    for (int ks = 0; ks < 6; ++ks) {
      int sec = (ks >> 1) << 7;               // 128B section base
      int off = ((ks & 1) << 6) | (lk << 4);  // 0..127 within section
      bf16x8 a0 = *(const bf16x8*)(ab + lr * 384 + sec + (off ^ swa));
      bf16x8 a1 = *(const bf16x8*)(ab + (16 + lr) * 384 + sec + (off ^ swa));
#pragma unroll
      for (int nt = 0; nt < 4; ++nt) {
        acc[0][nt] = __builtin_amdgcn_mfma_f32_16x16x32_bf16(
            a0, bw1[ks][nt], acc[0][nt], 0, 0, 0);
        acc[1][nt] = __builtin_amdgcn_mfma_f32_16x16x32_bf16(
            a1, bw1[ks][nt], acc[1][nt], 0, 0, 0);
      }
    }

    // ---- leaky, logits, f -> bf16 f-tile, e_ws + atomicMax
#pragma unroll
    for (int mt = 0; mt < 2; ++mt) {
#pragma unroll
      for (int r = 0; r < 4; ++r) {
        int m = mt * 16 + lk * 4 + r;
        char* rowp = fb + m * 512;
        int sw = swz(m);
        float p = 0.f;
#pragma unroll
        for (int nt = 0; nt < 4; ++nt) {
          int c = w * 64 + nt * 16 + lr;
          float v = acc[mt][nt][r];
          v = (v >= 0.f) ? v : NEG_SLOPE * v;
          p += v * av[nt];
          *(ushort*)(rowp + ((c * 2) ^ sw)) = f2bf(v);
        }
        p += __shfl_xor(p, 1);
        p += __shfl_xor(p, 2);
        p += __shfl_xor(p, 4);
        p += __shfl_xor(p, 8);
        if (lr == 0) {
          e_ws[(size_t)(e0 + m) * 4 + w] = p;
          atomicMaxF32(&emax[(size_t)dst[e0 + m] * 4 + w], p);
        }
      }
    }
    __syncthreads();

    // ---- GEMM2: out1 = f @ Wpe; wave w owns cols [w*16,(w+1)*16)
    f32x4 acc2[2];
    acc2[0] = (f32x4){0.f, 0.f, 0.f, 0.f};
    acc2[1] = (f32x4){0.f, 0.f, 0.f, 0.f};
#pragma unroll
    for (int ks = 0; ks < 8; ++ks) {
      int ko = (ks * 32 + lk * 8) * 2;
      bf16x8 a0 = *(const bf16x8*)(fb + lr * 512 + (ko ^ sw0));
      bf16x8 a1 = *(const bf16x8*)(fb + (16 + lr) * 512 + (ko ^ sw1));
      acc2[0] =
          __builtin_amdgcn_mfma_f32_16x16x32_bf16(a0, bw2[ks], acc2[0], 0, 0, 0);
      acc2[1] =
          __builtin_amdgcn_mfma_f32_16x16x32_bf16(a1, bw2[ks], acc2[1], 0, 0, 0);
    }

    // epilogue: + hH (bf16, from A-tile) + bpe; NON-TEMPORAL stores
#pragma unroll
    for (int mt = 0; mt < 2; ++mt)
#pragma unroll
      for (int r = 0; r < 4; ++r) {
        int m = mt * 16 + lk * 4 + r;
        int swmr = (m & 7) << 4;
        ushort h =
            *(const ushort*)(ab + m * 384 + ((((w * 16 + lr) * 2)) ^ swmr));
        size_t idx = (size_t)(e0 + m) * 64 + w * 16 + lr;
        __builtin_nontemporal_store(acc2[mt][r] + bf2f(h) + bpv, &out1[idx]);
      }
    __syncthreads();  // protect LDS before next tile's staging
  }
}

// ---------------- K3a: a = exp(e - emax[dst]); asum += a ----------------
__global__ void k3a(const float* __restrict__ e_ws, const int* __restrict__ dst,
                    const float* __restrict__ emax, float* __restrict__ a_ws,
                    float* __restrict__ asum, int E4) {
  int gid = blockIdx.x * 256 + threadIdx.x;
  if (gid >= E4) return;
  int e = gid >> 2, h = gid & 3;
  int dn = dst[e];
  float av = expf(e_ws[gid] - emax[dn * 4 + h]);
  a_ws[gid] = av;
  atomicAdd(&asum[dn * 4 + h], av);
}

// ---------------- K3b: out0[dst] += sum_h (a/asum) * hq[src,h,:] ------------
// (out0 pre-initialized to hE + bp_node by k_init; k4 eliminated)
__global__ __launch_bounds__(256) void k3b(
    const float* __restrict__ a_ws, const float* __restrict__ asum,
    const int* __restrict__ src, const int* __restrict__ dst,
    const ushort* __restrict__ hq, float* __restrict__ out0, int E) {
  int e = blockIdx.x * 4 + (threadIdx.x >> 6);
  if (e >= E) return;
  int d = threadIdx.x & 63;
  int sn = src[e], dn = dst[e];
  float w0 = a_ws[e * 4 + 0] / asum[dn * 4 + 0];
  float w1 = a_ws[e * 4 + 1] / asum[dn * 4 + 1];
  float w2 = a_ws[e * 4 + 2] / asum[dn * 4 + 2];
  float w3 = a_ws[e * 4 + 3] / asum[dn * 4 + 3];
  const ushort* hqp = hq + (size_t)sn * 256;
  float y = w0 * bf2f(hqp[d]) + w1 * bf2f(hqp[64 + d]) +
            w2 * bf2f(hqp[128 + d]) + w3 * bf2f(hqp[192 + d]);
  atomicAdd(&out0[(size_t)dn * 64 + d], y);
}

extern "C" void kernel_launch(void* const* d_in, const int* in_sizes, int n_in,
                              void* d_out, int out_size, void* d_ws, size_t ws_size,
                              hipStream_t stream) {
  const float* h_E    = (const float*)d_in[0];
  const float* h_H    = (const float*)d_in[1];
  const int*   src    = (const int*)d_in[2];
  const int*   dst    = (const int*)d_in[3];
  const float* W_node = (const float*)d_in[4];
  const float* b_node = (const float*)d_in[5];
  const float* W_ni   = (const float*)d_in[6];
  const float* W_nj   = (const float*)d_in[7];
  const float* W_fij  = (const float*)d_in[8];
  const float* attn   = (const float*)d_in[9];
  const float* Wp_node= (const float*)d_in[10];
  const float* bp_node= (const float*)d_in[11];
  const float* Wp_edge= (const float*)d_in[12];
  const float* bp_edge= (const float*)d_in[13];

  const int n = in_sizes[0] / 64;   // 50000 nodes
  const int e = in_sizes[1] / 64;   // 800000 edges

  // workspace layout
  ushort* ws_hEbf = (ushort*)d_ws;                      // n*64 bf16
  ushort* ws_hq   = ws_hEbf + (size_t)n * 64;           // n*256 bf16
  float*  ws_e    = (float*)(ws_hq + (size_t)n * 256);  // e*4
  float*  ws_a    = ws_e + (size_t)e * 4;               // e*4
  float*  ws_emax = ws_a + (size_t)e * 4;               // n*4
  float*  ws_asum = ws_emax + (size_t)n * 4;            // n*4
  ushort* ws_Wcat = (ushort*)(ws_asum + (size_t)n * 4); // 256*192 bf16
  ushort* ws_WpeT = ws_Wcat + 49152;                    // 64*256 bf16

  float* out0 = (float*)d_out;               // (n,64)
  float* out1 = out0 + (size_t)n * 64;       // (e,64)

  {
    int total = n * 64;
    k_init<<<(total + 255) / 256, 256, 0, stream>>>(ws_emax, ws_asum, h_E,
                                                    bp_node, out0, n);
  }
  k_prep<<<192, 256, 0, stream>>>(W_fij, W_ni, W_nj, Wp_edge, ws_Wcat, ws_WpeT);
  {
    int blocks = (n + 31) / 32;
    k_node<<<blocks, 256, 0, stream>>>(h_E, W_node, b_node, Wp_node,
                                       ws_hEbf, ws_hq, n);
  }
  {
    int ntiles = e / 32;  // E=800000 divisible by 32
    k_edge<<<1024, 256, 0, stream>>>(h_H, src, dst, ws_Wcat, attn, ws_WpeT,
                                     bp_edge, ws_hEbf, ws_e, ws_emax, out1,
                                     ntiles);
  }
  {
    int total = e * 4;
    k3a<<<(total + 255) / 256, 256, 0, stream>>>(ws_e, dst, ws_emax, ws_a,
                                                 ws_asum, total);
  }
  {
    int blocks = (e + 3) / 4;
    k3b<<<blocks, 256, 0, stream>>>(ws_a, ws_asum, src, dst, ws_hq, out0, e);
  }
}